// Round 5
// baseline (106.880 us; speedup 1.0000x reference)
//
#include <hip/hip_runtime.h>
#include <float.h>
#include <math.h>

// Problem constants (fixed by reference setup_inputs)
constexpr int NQ = 2048;    // queries
constexpr int ND = 65536;   // data points
constexpr int D  = 16;      // dims

// ---- MFMA-path tiling ----
// Wave = 64 queries x 512-point chunk. Block = 4 waves = 256 queries.
// grid = (NQ/256 = 8, SCH = 128) = 1024 blocks -> 4 blocks/CU, 16 waves/CU.
constexpr int SCH = 128;          // point chunks (grid.y)
constexpr int CP  = ND / SCH;     // 512 points per chunk
constexpr int TPW = CP / 32;      // 16 point-tiles (32 pts) per wave

typedef short bf16x8 __attribute__((ext_vector_type(8)));
typedef float f32x16 __attribute__((ext_vector_type(16)));

__device__ __forceinline__ unsigned short f2bf(float f) {  // RNE fp32->bf16
    unsigned u = __float_as_uint(f);
    u += 0x7FFFu + ((u >> 16) & 1u);
    return (unsigned short)(u >> 16);
}
__device__ __forceinline__ float bf2f(unsigned short h) {
    return __uint_as_float(((unsigned)h) << 16);
}

// ---------------------------------------------------------------------------
// Pack kernel (data only): Ppk[ND][32] = [ph(16)|pl(16)] bf16,
//                          nhf[ND]    = -0.5*||p||^2 (fp32)
// ---------------------------------------------------------------------------
__global__ __launch_bounds__(256) void pack_data(const float* __restrict__ data,
                                                 unsigned short* __restrict__ Ppk,
                                                 float* __restrict__ nhf) {
    const int p = blockIdx.x * 256 + threadIdx.x;
    const float4* r4 = (const float4*)(data + (size_t)p * D);
    float4 a = r4[0], b = r4[1], c = r4[2], e = r4[3];
    float v[16] = {a.x, a.y, a.z, a.w, b.x, b.y, b.z, b.w,
                   c.x, c.y, c.z, c.w, e.x, e.y, e.z, e.w};
    unsigned short row[32];
    float n = 0.f;
#pragma unroll
    for (int k = 0; k < 16; ++k) {
        n = fmaf(v[k], v[k], n);
        unsigned short h = f2bf(v[k]);
        row[k]      = h;
        row[16 + k] = f2bf(v[k] - bf2f(h));   // exact residual, rounded to bf16
    }
    uint4* w4 = (uint4*)(Ppk + (size_t)p * 32);
    const uint4* rr = (const uint4*)row;
    w4[0] = rr[0]; w4[1] = rr[1]; w4[2] = rr[2]; w4[3] = rr[3];
    nhf[p] = -0.5f * n;
}

// ---------------------------------------------------------------------------
// Main kernel: per wave, 64 queries (2 row-tiles) x one 512-point chunk.
//   best[q] = max_p ( x_q . p - 0.5*||p||^2 )   (argmin dist2 == argmax this)
// Each 32-pt B tile is loaded ONCE and feeds 6 MFMAs (2 row-tiles x 3 hi/lo
// combos: hh + lh + hl), halving B-fragment L1 traffic vs 32 rows/wave.
// C seeded with -0.5*||p||^2 (col-constant per lane).
// A-frag: lane holds x[qbase(+32) + (l&31)][ (l>>5)*8 + j ].
// C/D: col = lane&31, row = (reg&3) + 8*(reg>>2) + 4*(lane>>5)  [m74/m101].
// ---------------------------------------------------------------------------
__global__ __launch_bounds__(256, 4) void knn_mfma(const float* __restrict__ x,
                                                   const unsigned short* __restrict__ Ppk,
                                                   const float* __restrict__ nhf,
                                                   float* __restrict__ part) {
    const int tid  = threadIdx.x;
    const int w    = tid >> 6;
    const int l    = tid & 63;
    const int half = l >> 5;
    const int n31  = l & 31;
    const int qbase = blockIdx.x * 256 + w * 64;   // 4 waves x 64 queries
    const int pbase = blockIdx.y * CP;

    // Build A fragments (hi/lo bf16) for both row-tiles from raw fp32 x.
    bf16x8 a0h, a0l, a1h, a1l;
    {
        const float* xr0 = x + (size_t)(qbase + n31) * D + half * 8;
        const float* xr1 = x + (size_t)(qbase + 32 + n31) * D + half * 8;
        float4 p0 = *(const float4*)xr0, p1 = *(const float4*)(xr0 + 4);
        float4 q0 = *(const float4*)xr1, q1 = *(const float4*)(xr1 + 4);
        const float v0[8] = {p0.x, p0.y, p0.z, p0.w, p1.x, p1.y, p1.z, p1.w};
        const float v1[8] = {q0.x, q0.y, q0.z, q0.w, q1.x, q1.y, q1.z, q1.w};
#pragma unroll
        for (int k = 0; k < 8; ++k) {
            unsigned short h0 = f2bf(v0[k]);
            a0h[k] = (short)h0;
            a0l[k] = (short)f2bf(v0[k] - bf2f(h0));
            unsigned short h1 = f2bf(v1[k]);
            a1h[k] = (short)h1;
            a1l[k] = (short)f2bf(v1[k] - bf2f(h1));
        }
    }

    // B-side pointers (per-lane point column). Tile t: +t*1024 shorts.
    const unsigned short* bp = Ppk + (size_t)(pbase + n31) * 32 + half * 8;
    const float*          np = nhf + pbase + n31;

    f32x16 rbest0, rbest1;
#pragma unroll
    for (int r = 0; r < 16; ++r) { rbest0[r] = -FLT_MAX; rbest1[r] = -FLT_MAX; }

    // Software pipeline over tiles: prefetch t+1 while computing t.
    bf16x8 bh = *(const bf16x8*)bp;
    bf16x8 bl = *(const bf16x8*)(bp + 16);
    float  nv = *np;

    for (int t = 0; t < TPW; ++t) {
        bf16x8 nbh, nbl; float nnv;
        if (t + 1 < TPW) {
            const unsigned short* nb = bp + (size_t)(t + 1) * 1024;
            nbh = *(const bf16x8*)nb;
            nbl = *(const bf16x8*)(nb + 16);
            nnv = np[(size_t)(t + 1) * 32];
        }
        f32x16 c0, c1;
#pragma unroll
        for (int r = 0; r < 16; ++r) { c0[r] = nv; c1[r] = nv; }
        c0 = __builtin_amdgcn_mfma_f32_32x32x16_bf16(a0h, bh, c0, 0, 0, 0);
        c1 = __builtin_amdgcn_mfma_f32_32x32x16_bf16(a1h, bh, c1, 0, 0, 0);
        c0 = __builtin_amdgcn_mfma_f32_32x32x16_bf16(a0l, bh, c0, 0, 0, 0);
        c1 = __builtin_amdgcn_mfma_f32_32x32x16_bf16(a1l, bh, c1, 0, 0, 0);
        c0 = __builtin_amdgcn_mfma_f32_32x32x16_bf16(a0h, bl, c0, 0, 0, 0);
        c1 = __builtin_amdgcn_mfma_f32_32x32x16_bf16(a1h, bl, c1, 0, 0, 0);
#pragma unroll
        for (int r = 0; r < 16; ++r) {
            rbest0[r] = fmaxf(rbest0[r], c0[r]);
            rbest1[r] = fmaxf(rbest1[r], c1[r]);
        }
        bh = nbh; bl = nbl; nv = nnv;
    }

    // max over the 32 point-columns (lanes within each half)
#pragma unroll
    for (int r = 0; r < 16; ++r) {
        float v0 = rbest0[r], v1 = rbest1[r];
#pragma unroll
        for (int m = 1; m < 32; m <<= 1) {
            v0 = fmaxf(v0, __shfl_xor(v0, m, 32));
            v1 = fmaxf(v1, __shfl_xor(v1, m, 32));
        }
        rbest0[r] = v0; rbest1[r] = v1;
    }
    if (n31 == 0) {
        float* pp = part + (size_t)blockIdx.y * NQ + qbase + 4 * half;
#pragma unroll
        for (int r = 0; r < 16; ++r) {
            const int row = (r & 3) + 8 * (r >> 2);
            pp[row]      = rbest0[r];
            pp[row + 32] = rbest1[r];
        }
    }
}

// ---------------------------------------------------------------------------
// Final: reduce SCH chunks, dist2 = ||x||^2 - 2*best, bump.
// Coalesced across q each chunk iteration; 4 independent accumulators.
// ---------------------------------------------------------------------------
__global__ __launch_bounds__(256) void knn_final(const float* __restrict__ x,
                                                 const float* __restrict__ part,
                                                 float* __restrict__ out) {
    const int q = blockIdx.x * 256 + threadIdx.x;
    const float4* xr = (const float4*)(x + (size_t)q * D);
    float4 a = xr[0], b = xr[1], c = xr[2], e = xr[3];
    float x2 = a.x * a.x;
    x2 = fmaf(a.y, a.y, x2); x2 = fmaf(a.z, a.z, x2); x2 = fmaf(a.w, a.w, x2);
    x2 = fmaf(b.x, b.x, x2); x2 = fmaf(b.y, b.y, x2); x2 = fmaf(b.z, b.z, x2); x2 = fmaf(b.w, b.w, x2);
    x2 = fmaf(c.x, c.x, x2); x2 = fmaf(c.y, c.y, x2); x2 = fmaf(c.z, c.z, x2); x2 = fmaf(c.w, c.w, x2);
    x2 = fmaf(e.x, e.x, x2); x2 = fmaf(e.y, e.y, x2); x2 = fmaf(e.z, e.z, x2); x2 = fmaf(e.w, e.w, x2);

    float m0 = -FLT_MAX, m1 = -FLT_MAX, m2 = -FLT_MAX, m3 = -FLT_MAX;
#pragma unroll
    for (int cI = 0; cI < SCH; cI += 4) {
        m0 = fmaxf(m0, part[(size_t)(cI + 0) * NQ + q]);
        m1 = fmaxf(m1, part[(size_t)(cI + 1) * NQ + q]);
        m2 = fmaxf(m2, part[(size_t)(cI + 2) * NQ + q]);
        m3 = fmaxf(m3, part[(size_t)(cI + 3) * NQ + q]);
    }
    float mbest = fmaxf(fmaxf(m0, m1), fmaxf(m2, m3));

    float nn2  = fmaxf(fmaf(-2.f, mbest, x2), 0.f);
    float dist = sqrtf(fmaxf(nn2, 1e-12f));
    float bump = 0.f;
    if (dist < 2.0f) {                      // RADIUS = 2
        float denom = dist * dist - 4.0f;   // d^2 - r^2
        bump = expf(1.0f / denom + 0.25f);  // DECAY/denom + DECAY/r^2
    }
    out[q] = bump;
}

// ===========================================================================
// Fallback (fp32 scalar-pipe path) if workspace is too small for MFMA path.
// ===========================================================================
__global__ __launch_bounds__(256) void neg_half_norms(const float* __restrict__ data,
                                                      float* __restrict__ nhn) {
    const int p = blockIdx.x * 256 + threadIdx.x;
    const float4* r = (const float4*)(data + (size_t)p * D);
    float4 a = r[0], b = r[1], c = r[2], e = r[3];
    float n = a.x * a.x;
    n = fmaf(a.y, a.y, n); n = fmaf(a.z, a.z, n); n = fmaf(a.w, a.w, n);
    n = fmaf(b.x, b.x, n); n = fmaf(b.y, b.y, n); n = fmaf(b.z, b.z, n); n = fmaf(b.w, b.w, n);
    n = fmaf(c.x, c.x, n); n = fmaf(c.y, c.y, n); n = fmaf(c.z, c.z, n); n = fmaf(c.w, c.w, n);
    n = fmaf(e.x, e.x, n); n = fmaf(e.y, e.y, n); n = fmaf(e.z, e.z, n); n = fmaf(e.w, e.w, n);
    nhn[p] = -0.5f * n;
}

__global__ __launch_bounds__(256) void knn_partial_fb(const float* __restrict__ x,
                                                      const float* __restrict__ data,
                                                      const float* __restrict__ nhn,
                                                      float* __restrict__ part, int cp) {
    const int q     = blockIdx.x * 256 + threadIdx.x;
    const int pbase = blockIdx.y * cp;
    const float4* xr = (const float4*)(x + (size_t)q * D);
    const float4 xa = xr[0], xb = xr[1], xc = xr[2], xd = xr[3];
    const float* dp = data + (size_t)pbase * D;
    const float* np = nhn + pbase;
    float best = -FLT_MAX;
    for (int i = 0; i < cp; i += 4) {
#pragma unroll
        for (int j = 0; j < 4; ++j) {
            const float* r  = dp + (size_t)(i + j) * D;
            const float  hn = np[i + j];
            float ca = xa.x * r[0];
            ca = fmaf(xa.y, r[1], ca);  ca = fmaf(xa.z, r[2], ca);  ca = fmaf(xa.w, r[3], ca);
            ca = fmaf(xb.x, r[4], ca);  ca = fmaf(xb.y, r[5], ca);  ca = fmaf(xb.z, r[6], ca);
            ca = fmaf(xb.w, r[7], ca);
            float cb = fmaf(xc.x, r[8], hn);
            cb = fmaf(xc.y, r[9],  cb); cb = fmaf(xc.z, r[10], cb); cb = fmaf(xc.w, r[11], cb);
            cb = fmaf(xd.x, r[12], cb); cb = fmaf(xd.y, r[13], cb); cb = fmaf(xd.z, r[14], cb);
            cb = fmaf(xd.w, r[15], cb);
            best = fmaxf(best, ca + cb);
        }
    }
    part[(size_t)blockIdx.y * NQ + q] = best;
}

__global__ __launch_bounds__(256) void knn_final_fb(const float* __restrict__ x,
                                                    const float* __restrict__ part,
                                                    float* __restrict__ out, int S) {
    const int q = blockIdx.x * 256 + threadIdx.x;
    const float4* xr = (const float4*)(x + (size_t)q * D);
    float4 a = xr[0], b = xr[1], c = xr[2], e = xr[3];
    float x2 = a.x * a.x;
    x2 = fmaf(a.y, a.y, x2); x2 = fmaf(a.z, a.z, x2); x2 = fmaf(a.w, a.w, x2);
    x2 = fmaf(b.x, b.x, x2); x2 = fmaf(b.y, b.y, x2); x2 = fmaf(b.z, b.z, x2); x2 = fmaf(b.w, b.w, x2);
    x2 = fmaf(c.x, c.x, x2); x2 = fmaf(c.y, c.y, x2); x2 = fmaf(c.z, c.z, x2); x2 = fmaf(c.w, c.w, x2);
    x2 = fmaf(e.x, e.x, x2); x2 = fmaf(e.y, e.y, x2); x2 = fmaf(e.z, e.z, x2); x2 = fmaf(e.w, e.w, x2);
    float mb = -FLT_MAX;
    for (int cI = 0; cI < S; ++cI) mb = fmaxf(mb, part[(size_t)cI * NQ + q]);
    float nn2  = fmaxf(fmaf(-2.f, mb, x2), 0.f);
    float dist = sqrtf(fmaxf(nn2, 1e-12f));
    float bump = 0.f;
    if (dist < 2.0f) {
        float denom = dist * dist - 4.0f;
        bump = expf(1.0f / denom + 0.25f);
    }
    out[q] = bump;
}

extern "C" void kernel_launch(void* const* d_in, const int* in_sizes, int n_in,
                              void* d_out, int out_size, void* d_ws, size_t ws_size,
                              hipStream_t stream) {
    const float* x    = (const float*)d_in[0];   // [2048,16] fp32
    const float* data = (const float*)d_in[1];   // [65536,16] fp32
    float* out = (float*)d_out;                  // [2048] fp32

    // ws layout (bytes):
    //   Ppk  [0, 4 MiB)          ND*32 bf16
    //   nhf  [4 MiB, +256 KiB)   ND fp32
    //   part [+256 KiB)          SCH*NQ fp32 (1 MiB)
    const size_t off_nhf  = (size_t)ND * 32 * 2;             // 4194304
    const size_t off_part = off_nhf + (size_t)ND * 4;        // 4456448
    const size_t needed   = off_part + (size_t)SCH * NQ * 4; // 5505024

    if (ws_size >= needed) {
        unsigned short* Ppk = (unsigned short*)d_ws;
        float* nhf  = (float*)((char*)d_ws + off_nhf);
        float* part = (float*)((char*)d_ws + off_part);

        pack_data<<<ND / 256, 256, 0, stream>>>(data, Ppk, nhf);
        knn_mfma<<<dim3(NQ / 256, SCH), 256, 0, stream>>>(x, Ppk, nhf, part);
        knn_final<<<NQ / 256, 256, 0, stream>>>(x, part, out);
    } else {
        int S = 32;
        while (S > 1 && (size_t)(ND + S * NQ) * sizeof(float) > ws_size) S >>= 1;
        const int cp = ND / S;
        float* nhn  = (float*)d_ws;
        float* part = (float*)d_ws + ND;
        neg_half_norms<<<ND / 256, 256, 0, stream>>>(data, nhn);
        knn_partial_fb<<<dim3(NQ / 256, S), 256, 0, stream>>>(x, data, nhn, part, cp);
        knn_final_fb<<<NQ / 256, 256, 0, stream>>>(x, part, out, S);
    }
}

// Round 6
// 95.307 us; speedup vs baseline: 1.1214x; 1.1214x over previous
//
#include <hip/hip_runtime.h>
#include <float.h>
#include <math.h>

// Problem constants (fixed by reference setup_inputs)
constexpr int NQ = 2048;    // queries
constexpr int ND = 65536;   // data points
constexpr int D  = 16;      // dims

// ---- MFMA-path tiling ----
// Block = 4 waves x 32 DIFFERENT queries each (128 q/block), sharing one
// 1024-point chunk staged once into 64 KB LDS.
// grid = (NQ/128 = 16, SCH = 64) = 1024 blocks, 2 blocks/CU (LDS-bound).
constexpr int SCH = 64;           // point chunks (grid.y)
constexpr int CP  = ND / SCH;     // 1024 points per chunk
constexpr int TPC = CP / 32;      // 32 point-tiles (32 pts) per chunk
constexpr int CHUNK_B = TPC * 2048;  // 65536 B packed B-tiles per chunk

typedef short bf16x8 __attribute__((ext_vector_type(8)));
typedef float f32x16 __attribute__((ext_vector_type(16)));

__device__ __forceinline__ unsigned short f2bf(float f) {  // RNE fp32->bf16
    unsigned u = __float_as_uint(f);
    u += 0x7FFFu + ((u >> 16) & 1u);
    return (unsigned short)(u >> 16);
}
__device__ __forceinline__ float bf2f(unsigned short h) {
    return __uint_as_float(((unsigned)h) << 16);
}

// ---------------------------------------------------------------------------
// Pack kernel: data -> Ppk in LANE-CONSUMPTION order + transposed norms.
// Chunk c (64 KB) at c*65536. Tile t at t*2048:
//   [bh: 64 x 16B, entry l = dims[(l>>5)*8..+8) hi of point t*32+(l&31)]
//   [bl: same, lo residual] at +1024.
// nrmT[c][n31][t] = -0.5*||p||^2 for point c*1024 + t*32 + n31
//   -> lane n31 reads its 32 per-tile norms as 8 coalesced float4s.
// ---------------------------------------------------------------------------
__global__ __launch_bounds__(256) void pack_data(const float* __restrict__ data,
                                                 unsigned char* __restrict__ Ppk,
                                                 float* __restrict__ nrmT) {
    const int p = blockIdx.x * 256 + threadIdx.x;
    const float4* r4 = (const float4*)(data + (size_t)p * D);
    float4 a = r4[0], b = r4[1], c4 = r4[2], e = r4[3];
    float v[16] = {a.x, a.y, a.z, a.w, b.x, b.y, b.z, b.w,
                   c4.x, c4.y, c4.z, c4.w, e.x, e.y, e.z, e.w};
    unsigned short hi[16], lo[16];
    float n = 0.f;
#pragma unroll
    for (int k = 0; k < 16; ++k) {
        n = fmaf(v[k], v[k], n);
        unsigned short h = f2bf(v[k]);
        hi[k] = h;
        lo[k] = f2bf(v[k] - bf2f(h));   // exact residual, rounded to bf16
    }
    const int c   = p >> 10;        // chunk
    const int i   = p & 1023;       // point in chunk
    const int t   = i >> 5;         // tile in chunk
    const int n31 = i & 31;         // point in tile
    unsigned char* tb = Ppk + (size_t)c * CHUNK_B + (size_t)t * 2048;
    *(uint4*)(tb + (size_t)n31 * 16)               = *(const uint4*)&hi[0];
    *(uint4*)(tb + (size_t)(32 + n31) * 16)        = *(const uint4*)&hi[8];
    *(uint4*)(tb + 1024 + (size_t)n31 * 16)        = *(const uint4*)&lo[0];
    *(uint4*)(tb + 1024 + (size_t)(32 + n31) * 16) = *(const uint4*)&lo[8];
    nrmT[(size_t)c * 1024 + (size_t)n31 * 32 + t]  = -0.5f * n;
}

// ---------------------------------------------------------------------------
// Main kernel: stage chunk into LDS once (conflict-free lane*16 layout),
// then each of 4 waves scans all 32 tiles for ITS 32 queries.
//   best[q] = max_p ( x_q . p - 0.5*||p||^2 )   (argmin dist2 == argmax this)
// 3x mfma_f32_32x32x16_bf16 per tile (hh + lh + hl), C seeded with
// -0.5*||p||^2 (per-lane scalar, preloaded for all tiles).
// A-frag: lane holds x[qbase + (l&31)][ (l>>5)*8 + j ]  (verified R3/R4).
// C/D: col = lane&31, row = (reg&3) + 8*(reg>>2) + 4*(lane>>5)  [m74/m101].
// ---------------------------------------------------------------------------
__global__ __launch_bounds__(256, 2) void knn_mfma(const float* __restrict__ x,
                                                   const unsigned char* __restrict__ Ppk,
                                                   const float* __restrict__ nrmT,
                                                   float* __restrict__ part) {
    __shared__ unsigned char smem[CHUNK_B];   // 64 KB -> 2 blocks/CU

    const int tid  = threadIdx.x;
    const int w    = tid >> 6;
    const int l    = tid & 63;
    const int half = l >> 5;
    const int n31  = l & 31;
    const int qbase = blockIdx.x * 128 + w * 32;   // 4 waves x 32 queries

    // ---- Stage chunk: 16 rounds x 256 threads x 16 B = 64 KB ----
    {
        const unsigned char* src = Ppk + (size_t)blockIdx.y * CHUNK_B;
#pragma unroll
        for (int r = 0; r < 16; ++r) {
            const int off = r * 4096 + tid * 16;
            *(uint4*)(smem + off) = *(const uint4*)(src + off);
        }
    }

    // ---- Build A fragments (hi/lo bf16) from raw fp32 x (overlaps staging) ----
    bf16x8 axh, axl;
    {
        const float* xr = x + (size_t)(qbase + n31) * D + half * 8;
        float4 x0 = *(const float4*)xr;
        float4 x1 = *(const float4*)(xr + 4);
        const float xv[8] = {x0.x, x0.y, x0.z, x0.w, x1.x, x1.y, x1.z, x1.w};
#pragma unroll
        for (int k = 0; k < 8; ++k) {
            unsigned short h = f2bf(xv[k]);
            axh[k] = (short)h;
            axl[k] = (short)f2bf(xv[k] - bf2f(h));
        }
    }

    // ---- Preload this lane's 32 per-tile norms (8 coalesced float4s) ----
    float nvv[32];
    {
        const float4* np = (const float4*)(nrmT + (size_t)blockIdx.y * 1024 + (size_t)n31 * 32);
#pragma unroll
        for (int k = 0; k < 8; ++k) {
            float4 f = np[k];
            nvv[4 * k + 0] = f.x; nvv[4 * k + 1] = f.y;
            nvv[4 * k + 2] = f.z; nvv[4 * k + 3] = f.w;
        }
    }

    __syncthreads();   // staging complete

    f32x16 rbest;
#pragma unroll
    for (int r = 0; r < 16; ++r) rbest[r] = -FLT_MAX;

    // ---- Tile loop from LDS, depth-1 register prefetch ----
    bf16x8 bh = *(const bf16x8*)(smem + (size_t)l * 16);
    bf16x8 bl = *(const bf16x8*)(smem + 1024 + (size_t)l * 16);

#pragma unroll
    for (int t = 0; t < TPC; ++t) {
        bf16x8 nbh, nbl;
        if (t + 1 < TPC) {
            const unsigned char* nb = smem + (size_t)(t + 1) * 2048 + (size_t)l * 16;
            nbh = *(const bf16x8*)nb;
            nbl = *(const bf16x8*)(nb + 1024);
        }
        const float nv = nvv[t];
        f32x16 c;
#pragma unroll
        for (int r = 0; r < 16; ++r) c[r] = nv;   // seed with -0.5*||p||^2
        c = __builtin_amdgcn_mfma_f32_32x32x16_bf16(axh, bh, c, 0, 0, 0);
        c = __builtin_amdgcn_mfma_f32_32x32x16_bf16(axl, bh, c, 0, 0, 0);
        c = __builtin_amdgcn_mfma_f32_32x32x16_bf16(axh, bl, c, 0, 0, 0);
#pragma unroll
        for (int r = 0; r < 16; ++r) rbest[r] = fmaxf(rbest[r], c[r]);
        bh = nbh; bl = nbl;
    }

    // ---- max over the 32 point-columns (lanes within each half) ----
#pragma unroll
    for (int r = 0; r < 16; ++r) {
        float v = rbest[r];
#pragma unroll
        for (int m = 1; m < 32; m <<= 1) v = fmaxf(v, __shfl_xor(v, m, 32));
        rbest[r] = v;
    }
    if (n31 == 0) {
        float* pp = part + (size_t)blockIdx.y * NQ + qbase + 4 * half;
#pragma unroll
        for (int r = 0; r < 16; ++r) pp[(r & 3) + 8 * (r >> 2)] = rbest[r];
    }
}

// ---------------------------------------------------------------------------
// Final: reduce SCH chunks, dist2 = ||x||^2 - 2*best, bump.
// Coalesced across q each chunk iteration; 4 independent accumulators.
// ---------------------------------------------------------------------------
__global__ __launch_bounds__(256) void knn_final(const float* __restrict__ x,
                                                 const float* __restrict__ part,
                                                 float* __restrict__ out) {
    const int q = blockIdx.x * 256 + threadIdx.x;
    const float4* xr = (const float4*)(x + (size_t)q * D);
    float4 a = xr[0], b = xr[1], c = xr[2], e = xr[3];
    float x2 = a.x * a.x;
    x2 = fmaf(a.y, a.y, x2); x2 = fmaf(a.z, a.z, x2); x2 = fmaf(a.w, a.w, x2);
    x2 = fmaf(b.x, b.x, x2); x2 = fmaf(b.y, b.y, x2); x2 = fmaf(b.z, b.z, x2); x2 = fmaf(b.w, b.w, x2);
    x2 = fmaf(c.x, c.x, x2); x2 = fmaf(c.y, c.y, x2); x2 = fmaf(c.z, c.z, x2); x2 = fmaf(c.w, c.w, x2);
    x2 = fmaf(e.x, e.x, x2); x2 = fmaf(e.y, e.y, x2); x2 = fmaf(e.z, e.z, x2); x2 = fmaf(e.w, e.w, x2);

    float m0 = -FLT_MAX, m1 = -FLT_MAX, m2 = -FLT_MAX, m3 = -FLT_MAX;
#pragma unroll
    for (int cI = 0; cI < SCH; cI += 4) {
        m0 = fmaxf(m0, part[(size_t)(cI + 0) * NQ + q]);
        m1 = fmaxf(m1, part[(size_t)(cI + 1) * NQ + q]);
        m2 = fmaxf(m2, part[(size_t)(cI + 2) * NQ + q]);
        m3 = fmaxf(m3, part[(size_t)(cI + 3) * NQ + q]);
    }
    float mbest = fmaxf(fmaxf(m0, m1), fmaxf(m2, m3));

    float nn2  = fmaxf(fmaf(-2.f, mbest, x2), 0.f);
    float dist = sqrtf(fmaxf(nn2, 1e-12f));
    float bump = 0.f;
    if (dist < 2.0f) {                      // RADIUS = 2
        float denom = dist * dist - 4.0f;   // d^2 - r^2
        bump = expf(1.0f / denom + 0.25f);  // DECAY/denom + DECAY/r^2
    }
    out[q] = bump;
}

// ===========================================================================
// Fallback (fp32 scalar-pipe path) if workspace is too small for MFMA path.
// ===========================================================================
__global__ __launch_bounds__(256) void neg_half_norms(const float* __restrict__ data,
                                                      float* __restrict__ nhn) {
    const int p = blockIdx.x * 256 + threadIdx.x;
    const float4* r = (const float4*)(data + (size_t)p * D);
    float4 a = r[0], b = r[1], c = r[2], e = r[3];
    float n = a.x * a.x;
    n = fmaf(a.y, a.y, n); n = fmaf(a.z, a.z, n); n = fmaf(a.w, a.w, n);
    n = fmaf(b.x, b.x, n); n = fmaf(b.y, b.y, n); n = fmaf(b.z, b.z, n); n = fmaf(b.w, b.w, n);
    n = fmaf(c.x, c.x, n); n = fmaf(c.y, c.y, n); n = fmaf(c.z, c.z, n); n = fmaf(c.w, c.w, n);
    n = fmaf(e.x, e.x, n); n = fmaf(e.y, e.y, n); n = fmaf(e.z, e.z, n); n = fmaf(e.w, e.w, n);
    nhn[p] = -0.5f * n;
}

__global__ __launch_bounds__(256) void knn_partial_fb(const float* __restrict__ x,
                                                      const float* __restrict__ data,
                                                      const float* __restrict__ nhn,
                                                      float* __restrict__ part, int cp) {
    const int q     = blockIdx.x * 256 + threadIdx.x;
    const int pbase = blockIdx.y * cp;
    const float4* xr = (const float4*)(x + (size_t)q * D);
    const float4 xa = xr[0], xb = xr[1], xc = xr[2], xd = xr[3];
    const float* dp = data + (size_t)pbase * D;
    const float* np = nhn + pbase;
    float best = -FLT_MAX;
    for (int i = 0; i < cp; i += 4) {
#pragma unroll
        for (int j = 0; j < 4; ++j) {
            const float* r  = dp + (size_t)(i + j) * D;
            const float  hn = np[i + j];
            float ca = xa.x * r[0];
            ca = fmaf(xa.y, r[1], ca);  ca = fmaf(xa.z, r[2], ca);  ca = fmaf(xa.w, r[3], ca);
            ca = fmaf(xb.x, r[4], ca);  ca = fmaf(xb.y, r[5], ca);  ca = fmaf(xb.z, r[6], ca);
            ca = fmaf(xb.w, r[7], ca);
            float cb = fmaf(xc.x, r[8], hn);
            cb = fmaf(xc.y, r[9],  cb); cb = fmaf(xc.z, r[10], cb); cb = fmaf(xc.w, r[11], cb);
            cb = fmaf(xd.x, r[12], cb); cb = fmaf(xd.y, r[13], cb); cb = fmaf(xd.z, r[14], cb);
            cb = fmaf(xd.w, r[15], cb);
            best = fmaxf(best, ca + cb);
        }
    }
    part[(size_t)blockIdx.y * NQ + q] = best;
}

__global__ __launch_bounds__(256) void knn_final_fb(const float* __restrict__ x,
                                                    const float* __restrict__ part,
                                                    float* __restrict__ out, int S) {
    const int q = blockIdx.x * 256 + threadIdx.x;
    const float4* xr = (const float4*)(x + (size_t)q * D);
    float4 a = xr[0], b = xr[1], c = xr[2], e = xr[3];
    float x2 = a.x * a.x;
    x2 = fmaf(a.y, a.y, x2); x2 = fmaf(a.z, a.z, x2); x2 = fmaf(a.w, a.w, x2);
    x2 = fmaf(b.x, b.x, x2); x2 = fmaf(b.y, b.y, x2); x2 = fmaf(b.z, b.z, x2); x2 = fmaf(b.w, b.w, x2);
    x2 = fmaf(c.x, c.x, x2); x2 = fmaf(c.y, c.y, x2); x2 = fmaf(c.z, c.z, x2); x2 = fmaf(c.w, c.w, x2);
    x2 = fmaf(e.x, e.x, x2); x2 = fmaf(e.y, e.y, x2); x2 = fmaf(e.z, e.z, x2); x2 = fmaf(e.w, e.w, x2);
    float mb = -FLT_MAX;
    for (int cI = 0; cI < S; ++cI) mb = fmaxf(mb, part[(size_t)cI * NQ + q]);
    float nn2  = fmaxf(fmaf(-2.f, mb, x2), 0.f);
    float dist = sqrtf(fmaxf(nn2, 1e-12f));
    float bump = 0.f;
    if (dist < 2.0f) {
        float denom = dist * dist - 4.0f;
        bump = expf(1.0f / denom + 0.25f);
    }
    out[q] = bump;
}

extern "C" void kernel_launch(void* const* d_in, const int* in_sizes, int n_in,
                              void* d_out, int out_size, void* d_ws, size_t ws_size,
                              hipStream_t stream) {
    const float* x    = (const float*)d_in[0];   // [2048,16] fp32
    const float* data = (const float*)d_in[1];   // [65536,16] fp32
    float* out = (float*)d_out;                  // [2048] fp32

    // ws layout (bytes):
    //   Ppk  [0, 4 MiB)          SCH chunks x 64 KB (lane-consumption order)
    //   nrmT [4 MiB, +256 KiB)   SCH x 32 x 32 fp32 (transposed norms)
    //   part [+256 KiB)          SCH*NQ fp32 (512 KiB)
    const size_t off_nrm  = (size_t)SCH * CHUNK_B;           // 4194304
    const size_t off_part = off_nrm + (size_t)ND * 4;        // 4456448
    const size_t needed   = off_part + (size_t)SCH * NQ * 4; // 4980736

    if (ws_size >= needed) {
        unsigned char* Ppk = (unsigned char*)d_ws;
        float* nrmT = (float*)((char*)d_ws + off_nrm);
        float* part = (float*)((char*)d_ws + off_part);

        pack_data<<<ND / 256, 256, 0, stream>>>(data, Ppk, nrmT);
        knn_mfma<<<dim3(NQ / 128, SCH), 256, 0, stream>>>(x, Ppk, nrmT, part);
        knn_final<<<NQ / 256, 256, 0, stream>>>(x, part, out);
    } else {
        int S = 32;
        while (S > 1 && (size_t)(ND + S * NQ) * sizeof(float) > ws_size) S >>= 1;
        const int cp = ND / S;
        float* nhn  = (float*)d_ws;
        float* part = (float*)d_ws + ND;
        neg_half_norms<<<ND / 256, 256, 0, stream>>>(data, nhn);
        knn_partial_fb<<<dim3(NQ / 256, S), 256, 0, stream>>>(x, data, nhn, part, cp);
        knn_final_fb<<<NQ / 256, 256, 0, stream>>>(x, part, out, S);
    }
}